// Round 5
// baseline (92.464 us; speedup 1.0000x reference)
//
#include <hip/hip_runtime.h>
#include <hip/hip_bf16.h>
#include <stdint.h>

#define MDIM 16384
#define NDIM 1024
#define KDIM 1024
#define BM 128
#define BN 128
#define BK 64
#define NT (KDIM / BK)   // 16 K-tiles

typedef __bf16 bf16x8 __attribute__((ext_vector_type(8)));
typedef float f32x4 __attribute__((ext_vector_type(4)));
typedef uint  u32x4 __attribute__((ext_vector_type(4)));

#define GLOBAL_CPTR(p) ((const __attribute__((address_space(1))) void*)(p))
#define LDS_PTR(p)     ((__attribute__((address_space(3))) void*)(p))

// ---------------- fp32 -> bf16 (RNE) convert (used for W only) --------------
__device__ inline ushort f2bf_rne(float f) {
    union { float f; uint32_t u; } c; c.f = f;
    uint32_t u = c.u;
    return (ushort)((u + 0x7fffu + ((u >> 16) & 1u)) >> 16);
}

__global__ __launch_bounds__(256) void cvt_f32_bf16(const float* __restrict__ src,
                                                    ushort* __restrict__ dst, int n8) {
    int i = blockIdx.x * 256 + threadIdx.x;
    if (i >= n8) return;
    const float4* s4 = (const float4*)src;
    float4 a = s4[2 * i];
    float4 b = s4[2 * i + 1];
    union { ushort us[8]; uint4 u4; } p;
    p.us[0] = f2bf_rne(a.x); p.us[1] = f2bf_rne(a.y);
    p.us[2] = f2bf_rne(a.z); p.us[3] = f2bf_rne(a.w);
    p.us[4] = f2bf_rne(b.x); p.us[5] = f2bf_rne(b.y);
    p.us[6] = f2bf_rne(b.z); p.us[7] = f2bf_rne(b.w);
    ((uint4*)dst)[i] = p.u4;
}

__device__ inline uint pk2bf(float lo, float hi) {
    union { __hip_bfloat162 h2; uint u; } c;
    c.h2 = __float22bfloat162_rn(float2{lo, hi});
    return c.u;
}

// ---------------- fused 128x128 1-barrier/tile GEMM --------------------------
// C = A(MxK, fp32) * B^T (B = W bf16, NxK) + bias.
// 4 waves (2x2, wave-tile 64x64), 64 KiB LDS -> 2 blocks/CU (stagger = the
// latency-hiding mechanism).  A converted fp32->bf16 in-kernel (reg-staged,
// XOR-swizzled ds_write); B staged via global_load_lds (inverse-swizzled src).
// All main-loop waits counted; ONE s_barrier per K-tile.
__global__ __launch_bounds__(256, 2) void gemm_fused(const float* __restrict__ A,
                                                     const ushort* __restrict__ B,
                                                     const float* __restrict__ bias,
                                                     float* __restrict__ C) {
    __shared__ ushort As[2][BM * BK];   // 2 x 16 KiB
    __shared__ ushort Bs[2][BN * BK];   // 2 x 16 KiB   (total 64 KiB)

    const int tid  = threadIdx.x;
    const int lane = tid & 63;
    const int wave = tid >> 6;    // 0..3
    const int wr   = wave >> 1;   // 0..1 : M half (64 rows)
    const int wc   = wave & 1;    // 0..1 : N half (64 cols)
    const int l15  = lane & 15;
    const int l4   = lane >> 4;

    // T1: chunked XCD swizzle, bijective (1024 blocks, 128/XCD contiguous).
    const int lin  = blockIdx.x;
    const int swz  = (lin & 7) * 128 + (lin >> 3);
    const int brow = (swz >> 3) * BM;
    const int bcol = (swz & 7) * BN;

    // ---- A staging: thread covers 32 consecutive floats of one row.
    const int arow = tid >> 1;            // 0..127
    const int acb  = (tid & 1) * 64;      // byte col base of the 32-float span
    const int awsw = (arow & 7) << 4;
    const float* Ag = A + (size_t)(brow + arow) * KDIM + (tid & 1) * 32;

    // ---- B staging: global_load_lds, linear dest, inverse-swizzled source.
    const int brw = tid >> 3;             // 0..31
    const ushort* Bg = B + (size_t)(bcol + brw) * KDIM
                         + (((((tid & 7) * 16) ^ ((brw & 7) << 4))) >> 1);

    // ---- fragment ds_read byte offsets (swizzled)
    const int sw   = (l15 & 7) << 4;
    const int offk0 = (l4 * 16) ^ sw;
    const int offk1 = (64 + l4 * 16) ^ sw;

#define BARRIER __builtin_amdgcn_s_barrier()
#define LGKM0  asm volatile("s_waitcnt lgkmcnt(0)" ::: "memory")
#define VMC(n) asm volatile("s_waitcnt vmcnt(" #n ")" ::: "memory")
#define SCHED0 __builtin_amdgcn_sched_barrier(0)
#define GLD4(d, p) asm volatile("global_load_dwordx4 %0, %1, off" : "=v"(d) : "v"(p) : "memory")

    // 4 x global_load_lds: B tile 128x64 bf16, 4 KiB per issue (32 rows)
#define STG_B4(bb, t_) do { _Pragma("unroll") \
    for (int s_ = 0; s_ < 4; ++s_) \
        __builtin_amdgcn_global_load_lds( \
            GLOBAL_CPTR(Bg + (size_t)(s_ * 32) * KDIM + (t_) * BK), \
            LDS_PTR(&Bs[bb][s_ * 2048 + tid * 8]), 16, 0, 0); } while (0)

    // 8 x GLD4: A tile 128x64 fp32 (32 floats/thread, consecutive)
#define GLDA_T(t_) do { \
    const float* q_ = Ag + (size_t)(t_) * BK; _Pragma("unroll") \
    for (int j_ = 0; j_ < 8; ++j_) GLD4(ar[j_], q_ + 4 * j_); } while (0)

    // convert ar[0..7] -> 4 x u32x4 swizzled ds_writes
#define CVTW_T(bb) do { _Pragma("unroll") \
    for (int j_ = 0; j_ < 4; ++j_) { \
        u32x4 k_; \
        k_.x = pk2bf(ar[2*j_].x,   ar[2*j_].y);   k_.y = pk2bf(ar[2*j_].z,   ar[2*j_].w); \
        k_.z = pk2bf(ar[2*j_+1].x, ar[2*j_+1].y); k_.w = pk2bf(ar[2*j_+1].z, ar[2*j_+1].w); \
        *(u32x4*)((char*)&As[bb][0] + arow * 128 + ((acb + j_ * 16) ^ awsw)) = k_; } } while (0)

#define LOAD_FRAGS(bb) do { \
    const char* Ab_ = (const char*)&As[bb][0] + (wr * 64 + l15) * 128; \
    const char* Bb_ = (const char*)&Bs[bb][0] + (wc * 64 + l15) * 128; \
    _Pragma("unroll") \
    for (int i_ = 0; i_ < 4; ++i_) { \
        af[i_][0] = *(const bf16x8*)(Ab_ + i_ * 2048 + offk0); \
        af[i_][1] = *(const bf16x8*)(Ab_ + i_ * 2048 + offk1); \
        bf[i_][0] = *(const bf16x8*)(Bb_ + i_ * 2048 + offk0); \
        bf[i_][1] = *(const bf16x8*)(Bb_ + i_ * 2048 + offk1); } } while (0)

#define MFMA_ALL do { __builtin_amdgcn_s_setprio(1); _Pragma("unroll") \
    for (int kk_ = 0; kk_ < 2; ++kk_) { _Pragma("unroll") \
        for (int m_ = 0; m_ < 4; ++m_) { _Pragma("unroll") \
            for (int n_ = 0; n_ < 4; ++n_) \
                acc[m_][n_] = __builtin_amdgcn_mfma_f32_16x16x32_bf16( \
                    af[m_][kk_], bf[n_][kk_], acc[m_][n_], 0, 0, 0); } } \
    __builtin_amdgcn_s_setprio(0); } while (0)

    f32x4  acc[4][4] = {};   // 64 VGPR accumulator
    bf16x8 af[4][2];         // 32 VGPR A frags
    bf16x8 bf[4][2];         // 32 VGPR B frags
    f32x4  ar[8];            // 32 VGPR A reg-staging

    // ---- prologue: A(0)+B(0) staged to buf0; A(1) left in flight.
    GLDA_T(0);                 // A0 x8
    STG_B4(0, 0);              // +B0 x4 = 12
    VMC(4); SCHED0;            // retire A0 (B0 stays)
    CVTW_T(0);
    GLDA_T(1);                 // +A1 x8 -> [B0 x4, A1 x8]
    VMC(8);                    // retire B0 (A1 stays)
    LGKM0;
    BARRIER;                   // buf0 visible; invariant: outstanding = A(u+1) x8

    // ---- main loop: ONE barrier per tile, all waits counted.
#pragma unroll 1
    for (int u = 0; u < NT; ++u) {
        const int cur = u & 1;
        LOAD_FRAGS(cur);                               // 16 ds_read_b128 (issue early)
        if (u + 1 < NT) {
            STG_B4(cur ^ 1, u + 1);                    // -> [A(u+1) x8, B x4]
            VMC(4); SCHED0;                            // retire A(u+1) x8
            CVTW_T(cur ^ 1); SCHED0;
        }
        if (u + 2 < NT) GLDA_T(u + 2);                 // -> [B x4, A(u+2) x8]
        MFMA_ALL;                                      // compiler lgkm-waits frags
        if (u + 2 < NT)      { VMC(8); }               // retire B(u+1) x4
        else if (u + 1 < NT) { VMC(0); }
        LGKM0;                                         // my ds_writes visible
        BARRIER;
    }

    // ---- epilogue: C = acc + bias
    float bv[4];
#pragma unroll
    for (int n = 0; n < 4; ++n)
        bv[n] = bias[bcol + wc * 64 + n * 16 + l15];

#pragma unroll
    for (int m = 0; m < 4; ++m) {
        const int row0 = brow + wr * 64 + m * 16 + l4 * 4;
#pragma unroll
        for (int n = 0; n < 4; ++n) {
            const int col = bcol + wc * 64 + n * 16 + l15;
#pragma unroll
            for (int r = 0; r < 4; ++r)
                C[(size_t)(row0 + r) * NDIM + col] = acc[m][n][r] + bv[n];
        }
    }
}

// ---------------- naive fp32 fallback (only if ws too small) ----------------
__global__ __launch_bounds__(256) void gemm_naive(const float* __restrict__ x,
                                                  const float* __restrict__ w,
                                                  const float* __restrict__ bias,
                                                  float* __restrict__ out) {
    long o = (long)blockIdx.x * 256 + threadIdx.x;
    if (o >= (long)MDIM * NDIM) return;
    int b = (int)(o / NDIM), n = (int)(o % NDIM);
    const float* xr = x + (long)b * KDIM;
    const float* wr = w + (long)n * KDIM;
    float s = 0.f;
    for (int k = 0; k < KDIM; ++k) s += xr[k] * wr[k];
    out[o] = s + bias[n];
}

extern "C" void kernel_launch(void* const* d_in, const int* in_sizes, int n_in,
                              void* d_out, int out_size, void* d_ws, size_t ws_size,
                              hipStream_t stream) {
    const float* x    = (const float*)d_in[0];
    const float* w    = (const float*)d_in[1];
    const float* bias = (const float*)d_in[2];
    float* out = (float*)d_out;

    const size_t need = (size_t)NDIM * KDIM * sizeof(ushort);   // 2 MiB (W only)
    if (ws_size >= need) {
        ushort* wb = (ushort*)d_ws;
        const int n8w = NDIM * KDIM / 8;   // 131,072
        cvt_f32_bf16<<<n8w / 256, 256, 0, stream>>>(w, wb, n8w);
        const int nblk = (MDIM / BM) * (NDIM / BN);   // 128 x 8 = 1024
        gemm_fused<<<nblk, 256, 0, stream>>>(x, wb, bias, out);
    } else {
        const long total = (long)MDIM * NDIM;
        gemm_naive<<<(int)((total + 255) / 256), 256, 0, stream>>>(x, w, bias, out);
    }
}

// Round 6
// 60.356 us; speedup vs baseline: 1.5320x; 1.5320x over previous
//
#include <hip/hip_runtime.h>
#include <hip/hip_bf16.h>
#include <stdint.h>

#define MDIM 16384
#define NDIM 1024
#define KDIM 1024
#define BM 256
#define BN 256
#define BK 64
#define NT (KDIM / BK)   // 16 K-tiles

typedef __bf16 bf16x8 __attribute__((ext_vector_type(8)));
typedef float f32x4 __attribute__((ext_vector_type(4)));
typedef uint  u32x4 __attribute__((ext_vector_type(4)));

#define GLOBAL_CPTR(p) ((const __attribute__((address_space(1))) void*)(p))
#define LDS_PTR(p)     ((__attribute__((address_space(3))) void*)(p))

// ---------------- fp32 -> bf16 (RNE) convert (used for W only) --------------
__device__ inline ushort f2bf_rne(float f) {
    union { float f; uint32_t u; } c; c.f = f;
    uint32_t u = c.u;
    return (ushort)((u + 0x7fffu + ((u >> 16) & 1u)) >> 16);
}

__global__ __launch_bounds__(256) void cvt_f32_bf16(const float* __restrict__ src,
                                                    ushort* __restrict__ dst, int n8) {
    int i = blockIdx.x * 256 + threadIdx.x;
    if (i >= n8) return;
    const float4* s4 = (const float4*)src;
    float4 a = s4[2 * i];
    float4 b = s4[2 * i + 1];
    union { ushort us[8]; uint4 u4; } p;
    p.us[0] = f2bf_rne(a.x); p.us[1] = f2bf_rne(a.y);
    p.us[2] = f2bf_rne(a.z); p.us[3] = f2bf_rne(a.w);
    p.us[4] = f2bf_rne(b.x); p.us[5] = f2bf_rne(b.y);
    p.us[6] = f2bf_rne(b.z); p.us[7] = f2bf_rne(b.w);
    ((uint4*)dst)[i] = p.u4;
}

__device__ inline uint pk2bf(float lo, float hi) {
    union { __hip_bfloat162 h2; uint u; } c;
    c.h2 = __float22bfloat162_rn(float2{lo, hi});
    return c.u;
}

// ---------------- fused 256x256 GEMM, A-in-LDS / B-from-L2 -------------------
// C = A(MxK, fp32) * B^T (B = W bf16, NxK, 2 MB -> L2-resident) + bias.
// 8 waves (2M x 4N), BK=64.  A: reg-staged fp32, cvt->bf16, XOR-swizzled LDS
// (64 KiB, dbuf).  B: fragments loaded global->VGPR one tile ahead (no LDS).
// 2 phases + ONE barrier per K-tile.  All A-LDS hazards barrier-separated.
__global__ __launch_bounds__(512, 2) void gemm_bl2(const float* __restrict__ A,
                                                   const ushort* __restrict__ B,
                                                   const float* __restrict__ bias,
                                                   float* __restrict__ C) {
    __shared__ ushort As[2][BM * BK];   // 2 x 32 KiB (A only)

    const int tid  = threadIdx.x;
    const int lane = tid & 63;
    const int wave = tid >> 6;
    const int wr   = wave >> 2;   // 0..1 : M half (128 rows)
    const int wc   = wave & 3;    // 0..3 : N quarter (64 cols)
    const int l15  = lane & 15;
    const int l4   = lane >> 4;

    // T1: chunked XCD swizzle (bijective, 256 blocks): the 4 bcol-sharers of
    // an A-panel land on the same XCD.
    const int lin  = blockIdx.y * gridDim.x + blockIdx.x;   // 0..255
    const int swz  = (lin & 7) * 32 + (lin >> 3);
    const int brow = (swz >> 2) * BM;
    const int bcol = (swz & 3) * BN;

    // ---- A staging geometry (512 threads cover 256x64 fp32 in 8 GLD4)
    const int lrow = tid >> 3;           // 0..63
    const int lcb  = (tid & 7) * 16;     // byte col (pre-swizzle) in bf16 row
    const int swb  = (lrow & 7) << 4;
    const int wb0  = lrow * 128 + (lcb ^ swb);   // swizzled ds_write byte off
    const float* Ag = A + (size_t)(brow + lrow) * KDIM + (tid & 7) * 8;

    // ---- B fragment global source: lane reads 16B at row (col), k l4*8
    //      bcur[nh*4 + j*2 + kk]  <-  W[bcol + wc*64 + nh*32 + j*16 + l15][k]
    const ushort* Bg = B + (size_t)(bcol + wc * 64 + l15) * KDIM + l4 * 8;

    // ---- fragment ds_read byte offsets (swizzled)
    const int sw   = (l15 & 7) << 4;
    const int off0 = l15 * 128 + ((l4 * 16) ^ sw);
    const int off1 = l15 * 128 + (((l4 * 16) + 64) ^ sw);

#define BARRIER __builtin_amdgcn_s_barrier()
#define LGKM0  asm volatile("s_waitcnt lgkmcnt(0)" ::: "memory")
#define VMC0   asm volatile("s_waitcnt vmcnt(0)" ::: "memory")
#define SCHED0 __builtin_amdgcn_sched_barrier(0)
#define GLD4(d, p) asm volatile("global_load_dwordx4 %0, %1, off" : "=v"(d) : "v"(p) : "memory")
#define GLDB(d, p) asm volatile("global_load_dwordx4 %0, %1, off" : "=v"(d) : "v"(p) : "memory")

    // issue all 8 A-loads (256 rows x BK fp32) for K-tile t_ into ar[0..7]
#define GLDA_T(t_) do { \
    const float* q_ = Ag + (size_t)(t_) * BK; \
    GLD4(ar[0], q_);                       GLD4(ar[1], q_ + 4); \
    GLD4(ar[2], q_ + (size_t) 64 * KDIM);  GLD4(ar[3], q_ + (size_t) 64 * KDIM + 4); \
    GLD4(ar[4], q_ + (size_t)128 * KDIM);  GLD4(ar[5], q_ + (size_t)128 * KDIM + 4); \
    GLD4(ar[6], q_ + (size_t)192 * KDIM);  GLD4(ar[7], q_ + (size_t)192 * KDIM + 4); } while (0)

    // convert ar[0..7] and ds_write (swizzled) the full 256-row A tile
#define CVTW_T(bb) do { _Pragma("unroll") \
    for (int h_ = 0; h_ < 4; ++h_) { \
        u32x4 k_; \
        k_.x = pk2bf(ar[2*h_].x, ar[2*h_].y); k_.y = pk2bf(ar[2*h_].z, ar[2*h_].w); \
        k_.z = pk2bf(ar[2*h_+1].x, ar[2*h_+1].y); k_.w = pk2bf(ar[2*h_+1].z, ar[2*h_+1].w); \
        *(u32x4*)((char*)&As[bb][0] + h_ * 64 * 128 + wb0) = k_; } } while (0)

    // issue 8 B-fragment loads for K-tile t_ (consumed next tile's PH-A)
#define GLDB_T(t_) do { \
    const ushort* p_ = Bg + (size_t)(t_) * BK; _Pragma("unroll") \
    for (int nh_ = 0; nh_ < 2; ++nh_) { _Pragma("unroll") \
        for (int j_ = 0; j_ < 2; ++j_) { _Pragma("unroll") \
            for (int kk_ = 0; kk_ < 2; ++kk_) \
                GLDB(bcur[nh_*4 + j_*2 + kk_], \
                     p_ + (size_t)(nh_ * 32 + j_ * 16) * KDIM + kk_ * 32); } } } while (0)

    // ds_read one A m-half (8 x b128) into af
#define LOAD_A(bb, mh) do { _Pragma("unroll") \
    for (int i_ = 0; i_ < 4; ++i_) { \
        const char* pb_ = (const char*)&As[bb][0] + (wr * 128 + (mh) * 64 + i_ * 16) * 128; \
        af[i_][0] = *(const bf16x8*)(pb_ + off0); \
        af[i_][1] = *(const bf16x8*)(pb_ + off1); } } while (0)

    // 32 MFMA: both n-halves for m-half mh (B from bcur regs)
#define MFMA_H(mh) do { __builtin_amdgcn_s_setprio(1); _Pragma("unroll") \
    for (int i_ = 0; i_ < 4; ++i_) { _Pragma("unroll") \
        for (int nh_ = 0; nh_ < 2; ++nh_) { _Pragma("unroll") \
            for (int j_ = 0; j_ < 2; ++j_) { _Pragma("unroll") \
                for (int kk_ = 0; kk_ < 2; ++kk_) \
                    acc[(mh)*4 + i_][nh_*2 + j_] = __builtin_amdgcn_mfma_f32_16x16x32_bf16( \
                        af[i_][kk_], bcur[nh_*4 + j_*2 + kk_], \
                        acc[(mh)*4 + i_][nh_*2 + j_], 0, 0, 0); } } } \
    __builtin_amdgcn_s_setprio(0); } while (0)

    f32x4  acc[8][4] = {};   // 128 AGPR
    bf16x8 af[4][2];         // 32 VGPR  A frags (current m-half)
    bf16x8 bcur[8];          // 32 VGPR  B frags (whole tile, global-loaded)
    f32x4  ar[8];            // 32 VGPR  A reg-staging

    // ---- prologue: establish entry invariant for tile 0:
    //      As[0] staged; outstanding = [A(1)x8, B(0)x8]
    GLDA_T(0);
    VMC0; SCHED0;
    CVTW_T(0);
    GLDA_T(1);
    SCHED0;
    GLDB_T(0);
    LGKM0;
    BARRIER;

    // ---- main loop: 2 phases, ONE barrier per tile; VMC0 per tile retires
    //      [A(u+1), B(u)] both issued >= 1 tile-phase ago.
#pragma unroll 1
    for (int u = 0; u < NT; ++u) {
        const int cur = u & 1;
        // PH-A
        VMC0; SCHED0;                       // B(u), A(u+1) arrived
        LOAD_A(cur, 0);                     // 8 ds_read_b128
        MFMA_H(0);                          // 32 MFMA (compiler lgkm-waits)
        // PH-B
        LOAD_A(cur, 1);
        if (u + 1 < NT) { CVTW_T(cur ^ 1); SCHED0; }
        if (u + 2 < NT) { GLDA_T(u + 2); SCHED0; }
        MFMA_H(1);
        if (u + 1 < NT) { GLDB_T(u + 1); }  // into bcur: last use was MFMA_H(1)
        LGKM0;                              // ds_writes visible
        BARRIER;
    }

    // ---- epilogue: C = acc + bias
#pragma unroll
    for (int mh = 0; mh < 2; ++mh)
#pragma unroll
        for (int i = 0; i < 4; ++i)
#pragma unroll
            for (int nh = 0; nh < 2; ++nh)
#pragma unroll
                for (int j = 0; j < 2; ++j) {
                    f32x4 v = acc[mh * 4 + i][nh * 2 + j];
                    const int row0 = brow + wr * 128 + mh * 64 + i * 16 + l4 * 4;
                    const int col  = bcol + wc * 64 + nh * 32 + j * 16 + l15;
                    const float bb2 = bias[col];
#pragma unroll
                    for (int r = 0; r < 4; ++r)
                        C[(size_t)(row0 + r) * NDIM + col] = v[r] + bb2;
                }
}

// ---------------- naive fp32 fallback (only if ws too small) ----------------
__global__ __launch_bounds__(256) void gemm_naive(const float* __restrict__ x,
                                                  const float* __restrict__ w,
                                                  const float* __restrict__ bias,
                                                  float* __restrict__ out) {
    long o = (long)blockIdx.x * 256 + threadIdx.x;
    if (o >= (long)MDIM * NDIM) return;
    int b = (int)(o / NDIM), n = (int)(o % NDIM);
    const float* xr = x + (long)b * KDIM;
    const float* wr = w + (long)n * KDIM;
    float s = 0.f;
    for (int k = 0; k < KDIM; ++k) s += xr[k] * wr[k];
    out[o] = s + bias[n];
}

extern "C" void kernel_launch(void* const* d_in, const int* in_sizes, int n_in,
                              void* d_out, int out_size, void* d_ws, size_t ws_size,
                              hipStream_t stream) {
    const float* x    = (const float*)d_in[0];
    const float* w    = (const float*)d_in[1];
    const float* bias = (const float*)d_in[2];
    float* out = (float*)d_out;

    const size_t need = (size_t)NDIM * KDIM * sizeof(ushort);   // 2 MiB (W only)
    if (ws_size >= need) {
        ushort* wb = (ushort*)d_ws;
        const int n8w = NDIM * KDIM / 8;   // 131,072
        cvt_f32_bf16<<<n8w / 256, 256, 0, stream>>>(w, wb, n8w);
        dim3 grid(NDIM / BN, MDIM / BM);   // (4, 64) = 256 blocks
        gemm_bl2<<<grid, 512, 0, stream>>>(x, wb, bias, out);
    } else {
        const long total = (long)MDIM * NDIM;
        gemm_naive<<<(int)((total + 255) / 256), 256, 0, stream>>>(x, w, bias, out);
    }
}

// Round 7
// 50.224 us; speedup vs baseline: 1.8410x; 1.2017x over previous
//
#include <hip/hip_runtime.h>
#include <hip/hip_bf16.h>
#include <stdint.h>

#define MDIM 16384
#define NDIM 1024
#define KDIM 1024
#define BM 256
#define BN 256
#define BK 64
#define NT (KDIM / BK)   // 16 K-tiles

typedef __bf16 bf16x8 __attribute__((ext_vector_type(8)));
typedef float f32x4 __attribute__((ext_vector_type(4)));
typedef uint  u32x4 __attribute__((ext_vector_type(4)));

#define GLOBAL_CPTR(p) ((const __attribute__((address_space(1))) void*)(p))
#define LDS_PTR(p)     ((__attribute__((address_space(3))) void*)(p))

// ---------------- fp32 -> bf16 (RNE) convert (used for W only) --------------
__device__ inline ushort f2bf_rne(float f) {
    union { float f; uint32_t u; } c; c.f = f;
    uint32_t u = c.u;
    return (ushort)((u + 0x7fffu + ((u >> 16) & 1u)) >> 16);
}

__global__ __launch_bounds__(256) void cvt_f32_bf16(const float* __restrict__ src,
                                                    ushort* __restrict__ dst, int n8) {
    int i = blockIdx.x * 256 + threadIdx.x;
    if (i >= n8) return;
    const float4* s4 = (const float4*)src;
    float4 a = s4[2 * i];
    float4 b = s4[2 * i + 1];
    union { ushort us[8]; uint4 u4; } p;
    p.us[0] = f2bf_rne(a.x); p.us[1] = f2bf_rne(a.y);
    p.us[2] = f2bf_rne(a.z); p.us[3] = f2bf_rne(a.w);
    p.us[4] = f2bf_rne(b.x); p.us[5] = f2bf_rne(b.y);
    p.us[6] = f2bf_rne(b.z); p.us[7] = f2bf_rne(b.w);
    ((uint4*)dst)[i] = p.u4;
}

__device__ inline uint pk2bf(float lo, float hi) {
    union { __hip_bfloat162 h2; uint u; } c;
    c.h2 = __float22bfloat162_rn(float2{lo, hi});
    return c.u;
}

// ---------------- fused 256x256 GEMM, ONE barrier per K-tile -----------------
// C = A(MxK, fp32) * B^T (B = W bf16, NxK) + bias.
// 8 waves (2M x 4N).  A: reg-staged fp32 -> cvt bf16 -> XOR-swizzled LDS.
// B: global_load_lds (inverse-swizzled source).  Double-buffered LDS (128 KiB).
// Within a tile all waves free-run (reads/stage/cvt/MFMA overlap across waves);
// the single tile-end barrier + counted vmcnt carries all cross-tile hazards.
__global__ __launch_bounds__(512, 2) void gemm_1b(const float* __restrict__ A,
                                                  const ushort* __restrict__ B,
                                                  const float* __restrict__ bias,
                                                  float* __restrict__ C) {
    __shared__ ushort As[2][BM * BK];   // 2 x 32 KiB
    __shared__ ushort Bs[2][BN * BK];   // 2 x 32 KiB

    const int tid  = threadIdx.x;
    const int lane = tid & 63;
    const int wave = tid >> 6;
    const int wr   = wave >> 2;   // 0..1 : M half (128 rows)
    const int wc   = wave & 3;    // 0..3 : N quarter (64 cols)
    const int l15  = lane & 15;
    const int l4   = lane >> 4;

    // T1: chunked XCD swizzle (bijective, 256 blocks % 8 == 0)
    const int lin  = blockIdx.y * gridDim.x + blockIdx.x;   // 0..255
    const int swz  = (lin & 7) * 32 + (lin >> 3);
    const int brow = (swz >> 2) * BM;
    const int bcol = (swz & 3) * BN;

    // ---- A staging geometry (512 threads cover 256x64 fp32 in 8 GLD4)
    const int lrow = tid >> 3;           // 0..63
    const int lcb  = (tid & 7) * 16;     // byte col (pre-swizzle) in bf16 row
    const int swb  = (lrow & 7) << 4;
    const int wb0  = lrow * 128 + (lcb ^ swb);   // swizzled ds_write byte off
    const float* Ag = A + (size_t)(brow + lrow) * KDIM + (tid & 7) * 8;

    // ---- B staging: global_load_lds linear dest, inverse-swizzled source
    const ushort* Bsrc = B + (size_t)(bcol + lrow) * KDIM + ((lcb ^ swb) >> 1);

    // ---- fragment ds_read byte offsets (swizzled)
    const int sw   = (l15 & 7) << 4;
    const int off0 = l15 * 128 + ((l4 * 16) ^ sw);
    const int off1 = l15 * 128 + (((l4 * 16) + 64) ^ sw);

#define BARRIER __builtin_amdgcn_s_barrier()
#define LGKM0  asm volatile("s_waitcnt lgkmcnt(0)" ::: "memory")
#define VMC(n) asm volatile("s_waitcnt vmcnt(" #n ")" ::: "memory")
#define SCHED0 __builtin_amdgcn_sched_barrier(0)
#define GLD4(d, p) asm volatile("global_load_dwordx4 %0, %1, off" : "=v"(d) : "v"(p) : "memory")

    // B tile 256x64 bf16 = 32 KiB staged in 4 global_load_lds issues
#define STG_B4(bb, t_) do { _Pragma("unroll") \
    for (int s_ = 0; s_ < 4; ++s_) \
        __builtin_amdgcn_global_load_lds( \
            GLOBAL_CPTR(Bsrc + (size_t)(s_ * 64) * KDIM + (t_) * BK), \
            LDS_PTR(&Bs[bb][s_ * 4096 + tid * 8]), 16, 0, 0); } while (0)

    // issue all 8 A-loads (256 rows x BK fp32) for K-tile t_ into ar[0..7]
#define GLDA_T(t_) do { \
    const float* q_ = Ag + (size_t)(t_) * BK; \
    GLD4(ar[0], q_);                       GLD4(ar[1], q_ + 4); \
    GLD4(ar[2], q_ + (size_t) 64 * KDIM);  GLD4(ar[3], q_ + (size_t) 64 * KDIM + 4); \
    GLD4(ar[4], q_ + (size_t)128 * KDIM);  GLD4(ar[5], q_ + (size_t)128 * KDIM + 4); \
    GLD4(ar[6], q_ + (size_t)192 * KDIM);  GLD4(ar[7], q_ + (size_t)192 * KDIM + 4); } while (0)

    // convert ar[0..7] and ds_write (swizzled) the full 256-row A tile
#define CVTW_T(bb) do { _Pragma("unroll") \
    for (int h_ = 0; h_ < 4; ++h_) { \
        u32x4 k_; \
        k_.x = pk2bf(ar[2*h_].x, ar[2*h_].y); k_.y = pk2bf(ar[2*h_].z, ar[2*h_].w); \
        k_.z = pk2bf(ar[2*h_+1].x, ar[2*h_+1].y); k_.w = pk2bf(ar[2*h_+1].z, ar[2*h_+1].w); \
        *(u32x4*)((char*)&As[bb][0] + h_ * 64 * 128 + wb0) = k_; } } while (0)

    // ds_read one A m-half (8 x b128) into af
#define LOAD_A(bb, mh) do { _Pragma("unroll") \
    for (int i_ = 0; i_ < 4; ++i_) { \
        const char* pb_ = (const char*)&As[bb][0] + (wr * 128 + (mh) * 64 + i_ * 16) * 128; \
        af[i_][0] = *(const bf16x8*)(pb_ + off0); \
        af[i_][1] = *(const bf16x8*)(pb_ + off1); } } while (0)

    // ds_read ALL B frags (both n-halves, 8 x b128) into bfr
#define LOAD_B_ALL(bb) do { _Pragma("unroll") \
    for (int nh_ = 0; nh_ < 2; ++nh_) { _Pragma("unroll") \
        for (int j_ = 0; j_ < 2; ++j_) { \
            const char* pb_ = (const char*)&Bs[bb][0] + (wc * 64 + nh_ * 32 + j_ * 16) * 128; \
            bfr[nh_][j_][0] = *(const bf16x8*)(pb_ + off0); \
            bfr[nh_][j_][1] = *(const bf16x8*)(pb_ + off1); } } } while (0)

    // 32 MFMA: both n-halves for m-half mh
#define MFMA_H(mh) do { __builtin_amdgcn_s_setprio(1); _Pragma("unroll") \
    for (int i_ = 0; i_ < 4; ++i_) { _Pragma("unroll") \
        for (int nh_ = 0; nh_ < 2; ++nh_) { _Pragma("unroll") \
            for (int j_ = 0; j_ < 2; ++j_) { _Pragma("unroll") \
                for (int kk_ = 0; kk_ < 2; ++kk_) \
                    acc[(mh)*4 + i_][nh_*2 + j_] = __builtin_amdgcn_mfma_f32_16x16x32_bf16( \
                        af[i_][kk_], bfr[nh_][j_][kk_], \
                        acc[(mh)*4 + i_][nh_*2 + j_], 0, 0, 0); } } } \
    __builtin_amdgcn_s_setprio(0); } while (0)

    f32x4  acc[8][4] = {};   // 128 AGPR
    bf16x8 af[4][2];         // 32 VGPR  A frags (current m-half, reloaded)
    bf16x8 bfr[2][2][2];     // 32 VGPR  B frags (whole tile)
    f32x4  ar[8];            // 32 VGPR  A reg-staging

    // ---- prologue: As[0]/Bs[0] staged; leave A(1)x8 in flight.
    GLDA_T(0);                 // A0 x8
    STG_B4(0, 0);              // +B0 x4 = 12
    VMC(4); SCHED0;            // retire A0 (B0 stays)
    CVTW_T(0);
    SCHED0;
    GLDA_T(1);                 // +A1 x8 -> [B0 x4, A1 x8]
    VMC(8);                    // retire B0 (A1 stays)
    LGKM0;
    BARRIER;                   // invariant: outstanding = A(u+1) x8

    // ---- main loop: ONE barrier per K-tile; all waits counted.
#pragma unroll 1
    for (int u = 0; u < NT; ++u) {
        const int cur = u & 1;
        LOAD_A(cur, 0);                          // 8 ds_read_b128
        LOAD_B_ALL(cur);                         // 8 ds_read_b128
        MFMA_H(0);                               // 32 MFMA (fine-grained lgkm)
        LOAD_A(cur, 1);                          // 8 ds_read_b128
        if (u + 1 < NT) {
            STG_B4(cur ^ 1, u + 1);              // [A(u+1)x8, Bx4]
            VMC(4); SCHED0;                      // retire A(u+1)x8
            CVTW_T(cur ^ 1); SCHED0;             // cvt + swizzled ds_write
        }
        if (u + 2 < NT) { GLDA_T(u + 2); SCHED0; }  // [Bx4, A(u+2)x8]
        MFMA_H(1);                               // 32 MFMA
        if (u + 2 < NT)      { VMC(8); }         // retire B(u+1)x4
        else if (u + 1 < NT) { VMC(0); }
        if (u + 1 < NT) { LGKM0; BARRIER; }
    }

    // ---- epilogue: C = acc + bias
#pragma unroll
    for (int mh = 0; mh < 2; ++mh)
#pragma unroll
        for (int i = 0; i < 4; ++i)
#pragma unroll
            for (int nh = 0; nh < 2; ++nh)
#pragma unroll
                for (int j = 0; j < 2; ++j) {
                    f32x4 v = acc[mh * 4 + i][nh * 2 + j];
                    const int row0 = brow + wr * 128 + mh * 64 + i * 16 + l4 * 4;
                    const int col  = bcol + wc * 64 + nh * 32 + j * 16 + l15;
                    const float bb2 = bias[col];
#pragma unroll
                    for (int r = 0; r < 4; ++r)
                        C[(size_t)(row0 + r) * NDIM + col] = v[r] + bb2;
                }
}

// ---------------- naive fp32 fallback (only if ws too small) ----------------
__global__ __launch_bounds__(256) void gemm_naive(const float* __restrict__ x,
                                                  const float* __restrict__ w,
                                                  const float* __restrict__ bias,
                                                  float* __restrict__ out) {
    long o = (long)blockIdx.x * 256 + threadIdx.x;
    if (o >= (long)MDIM * NDIM) return;
    int b = (int)(o / NDIM), n = (int)(o % NDIM);
    const float* xr = x + (long)b * KDIM;
    const float* wr = w + (long)n * KDIM;
    float s = 0.f;
    for (int k = 0; k < KDIM; ++k) s += xr[k] * wr[k];
    out[o] = s + bias[n];
}

extern "C" void kernel_launch(void* const* d_in, const int* in_sizes, int n_in,
                              void* d_out, int out_size, void* d_ws, size_t ws_size,
                              hipStream_t stream) {
    const float* x    = (const float*)d_in[0];
    const float* w    = (const float*)d_in[1];
    const float* bias = (const float*)d_in[2];
    float* out = (float*)d_out;

    const size_t need = (size_t)NDIM * KDIM * sizeof(ushort);   // 2 MiB (W only)
    if (ws_size >= need) {
        ushort* wb = (ushort*)d_ws;
        const int n8w = NDIM * KDIM / 8;   // 131,072
        cvt_f32_bf16<<<n8w / 256, 256, 0, stream>>>(w, wb, n8w);
        dim3 grid(NDIM / BN, MDIM / BM);   // (4, 64) = 256 blocks
        gemm_1b<<<grid, 512, 0, stream>>>(x, wb, bias, out);
    } else {
        const long total = (long)MDIM * NDIM;
        gemm_naive<<<(int)((total + 255) / 256), 256, 0, stream>>>(x, w, bias, out);
    }
}